// Round 2
// baseline (936.719 us; speedup 1.0000x reference)
//
#include <hip/hip_runtime.h>
#include <hip/hip_bf16.h>

#define S_  2048
#define DM_ 512
#define H_  8
#define DH_ 64
#define MF_ 64
#define DFF_ 2048
#define L_  2
#define CT_ 64          // chunk length for causal linear attention
#define NC_ (S_ / CT_)  // 32 chunks
#define EPS_ 1e-6f
#define LN_EPS_ 1e-5f

// ---------------------------------------------------------------- copy in
__global__ __launch_bounds__(256) void copy_kernel(const float* __restrict__ x,
                                                   float* __restrict__ o) {
  int i = blockIdx.x * 256 + threadIdx.x;
  o[i] = x[i];
}

// ---------------------------------------------------------------- GEMM
// C[M,N] = act(A[M,K] @ W[K,N] + bias[N] (+ Res[M,N]))
// 64x64 tile, 256 thr, 4x4 per thread. All fp32.
template<bool RELU, bool HAS_RES>
__global__ __launch_bounds__(256) void gemm_kernel(
    const float* __restrict__ A, const float* __restrict__ W,
    const float* __restrict__ bias, const float* __restrict__ Res,
    float* __restrict__ C, int K, int N) {
  __shared__ float As[16][68];   // [k][m], stride 68: conflict-free column reads
  __shared__ float Bs[16][64];   // [k][n]
  const int t = threadIdx.x;
  const int n0 = blockIdx.x * 64, m0 = blockIdx.y * 64;
  const int tm = t >> 4, tn = t & 15;
  const int ak = t & 15, am = t >> 4;   // A-load: k=ak, rows am+16i
  const int bn = t & 63, bk = t >> 6;   // B-load: n=bn, k=bk+4i

  float acc[4][4];
#pragma unroll
  for (int i = 0; i < 4; ++i)
#pragma unroll
    for (int j = 0; j < 4; ++j) acc[i][j] = 0.f;

  for (int k0 = 0; k0 < K; k0 += 16) {
#pragma unroll
    for (int i = 0; i < 4; ++i)
      As[ak][am + 16 * i] = A[(size_t)(m0 + am + 16 * i) * K + k0 + ak];
#pragma unroll
    for (int i = 0; i < 4; ++i)
      Bs[bk + 4 * i][bn] = W[(size_t)(k0 + bk + 4 * i) * N + n0 + bn];
    __syncthreads();
#pragma unroll
    for (int kk = 0; kk < 16; ++kk) {
      float a[4], b[4];
#pragma unroll
      for (int i = 0; i < 4; ++i) a[i] = As[kk][4 * tm + i];
#pragma unroll
      for (int j = 0; j < 4; ++j) b[j] = Bs[kk][4 * tn + j];
#pragma unroll
      for (int i = 0; i < 4; ++i)
#pragma unroll
        for (int j = 0; j < 4; ++j) acc[i][j] += a[i] * b[j];
    }
    __syncthreads();
  }

#pragma unroll
  for (int i = 0; i < 4; ++i) {
    int row = m0 + 4 * tm + i;
#pragma unroll
    for (int j = 0; j < 4; ++j) {
      int col = n0 + 4 * tn + j;
      float v = acc[i][j] + bias[col];
      if (HAS_RES) v += Res[(size_t)row * N + col];
      if (RELU) v = fmaxf(v, 0.f);
      C[(size_t)row * N + col] = v;
    }
  }
}

// ---------------------------------------------------------------- FAVOR+
// P[s, h*M+m] = exp(xs@omega - 0.5*|xs|^2) * M^-0.5,  xs = Q[s,h,:] * DH^-0.25
__global__ __launch_bounds__(512) void favor_kernel(const float* __restrict__ Q,
                                                    const float* __restrict__ omega,
                                                    float* __restrict__ P) {
  __shared__ float qs[DM_];
  __shared__ float om[DH_ * MF_];
  const int t = threadIdx.x, s = blockIdx.x;
  qs[t] = Q[(size_t)s * DM_ + t] * 0.35355339059327373f;  // 64^-0.25
  for (int i = t; i < DH_ * MF_; i += 512) om[i] = omega[i];
  __syncthreads();
  const int h = t >> 6, m = t & 63;
  const float* qh = qs + h * DH_;
  float nrm = 0.f, u = 0.f;
#pragma unroll 8
  for (int d = 0; d < DH_; ++d) {
    float x = qh[d];
    nrm += x * x;
    u += x * om[d * MF_ + m];
  }
  P[(size_t)s * DM_ + t] = expf(u - 0.5f * nrm) * 0.125f;  // 64^-0.5
}

// ---------------------------------------------------------------- chunk sums
// Per (chunk c, head h): KVc[m][d] = sum_t pk[t,m] v[t,d]; Kc[m] = sum_t pk[t,m]
__global__ __launch_bounds__(256) void chunk_sums(const float* __restrict__ PK,
                                                  const float* __restrict__ V,
                                                  float* __restrict__ KVc,
                                                  float* __restrict__ Kc) {
  const int c = blockIdx.x, h = blockIdx.y, t = threadIdx.x;
  __shared__ float pk[CT_][MF_];
  __shared__ float vs[CT_][DH_];
  for (int i = t; i < CT_ * MF_; i += 256) {
    int tt = i >> 6, m = i & 63;
    pk[tt][m] = PK[(size_t)(c * CT_ + tt) * DM_ + h * MF_ + m];
    vs[tt][m] = V[(size_t)(c * CT_ + tt) * DM_ + h * DH_ + m];
  }
  __syncthreads();
  const int m = t >> 2, dg = t & 3;
  float acc[16];
#pragma unroll
  for (int i = 0; i < 16; ++i) acc[i] = 0.f;
  float ks = 0.f;
  for (int tt = 0; tt < CT_; ++tt) {
    float p = pk[tt][m];
    ks += p;
    const float* vr = &vs[tt][dg * 16];
#pragma unroll
    for (int i = 0; i < 16; ++i) acc[i] += p * vr[i];
  }
  float* kvout = KVc + ((size_t)(h * NC_ + c)) * MF_ * DH_ + m * DH_ + dg * 16;
#pragma unroll
  for (int i = 0; i < 16; ++i) kvout[i] = acc[i];
  if (dg == 0) Kc[(size_t)(h * NC_ + c) * MF_ + m] = ks;
}

// ---------------------------------------------------------------- prefix scan
// In-place: chunk sums -> EXCLUSIVE prefix over chunks, per head.
__global__ __launch_bounds__(256) void prefix_kernel(float* __restrict__ KVc,
                                                     float* __restrict__ Kc) {
  const int h = blockIdx.x, t = threadIdx.x;
  for (int e = t; e < MF_ * DH_; e += 256) {
    float run = 0.f;
    for (int c = 0; c < NC_; ++c) {
      float* p = KVc + ((size_t)(h * NC_ + c)) * MF_ * DH_ + e;
      float tmp = *p; *p = run; run += tmp;
    }
  }
  if (t < MF_) {
    float run = 0.f;
    for (int c = 0; c < NC_; ++c) {
      float* p = Kc + (size_t)(h * NC_ + c) * MF_ + t;
      float tmp = *p; *p = run; run += tmp;
    }
  }
}

// ---------------------------------------------------------------- attention out
// num[s,d] = pq[s]·KVprefix[:,d] + sum_{tt<=s} (pq[s]·pk[tt]) v[tt,d]
// den[s]   = pq[s]·Kprefix + sum_{tt<=s} (pq[s]·pk[tt]) + eps
__global__ __launch_bounds__(256) void attn_out(const float* __restrict__ PQ,
                                                const float* __restrict__ PK,
                                                const float* __restrict__ V,
                                                const float* __restrict__ KVc,
                                                const float* __restrict__ Kc,
                                                float* __restrict__ Aout) {
  const int c = blockIdx.x, h = blockIdx.y, t = threadIdx.x;
  __shared__ float pq[CT_][MF_ + 1];
  __shared__ float pkv[CT_][MF_ + 1];  // pk in phase 1, v in phase 2
  __shared__ float Tm[CT_][CT_ + 1];
  __shared__ float den[CT_];

  for (int i = t; i < CT_ * MF_; i += 256) {
    int s = i >> 6, m = i & 63;
    pq[s][m] = PQ[(size_t)(c * CT_ + s) * DM_ + h * MF_ + m];
    pkv[s][m] = PK[(size_t)(c * CT_ + s) * DM_ + h * MF_ + m];
  }
  __syncthreads();
  // phase 1: lower-triangular scores
  for (int i = t; i < CT_ * CT_; i += 256) {
    int s = i >> 6, tt = i & 63;
    float d = 0.f;
    if (tt <= s) {
#pragma unroll 8
      for (int m = 0; m < MF_; ++m) d += pq[s][m] * pkv[tt][m];
    }
    Tm[s][tt] = d;
  }
  __syncthreads();
  // den (threads 0..63) while everyone reloads V into pkv
  if (t < CT_) {
    const int s = t;
    float d = EPS_;
    const float* kc = Kc + (size_t)(h * NC_ + c) * MF_;
    for (int m = 0; m < MF_; ++m) d += pq[s][m] * kc[m];
    for (int tt = 0; tt <= s; ++tt) d += Tm[s][tt];
    den[s] = d;
  }
  for (int i = t; i < CT_ * MF_; i += 256) {
    int s = i >> 6, m = i & 63;
    pkv[s][m] = V[(size_t)(c * CT_ + s) * DM_ + h * DH_ + m];
  }
  __syncthreads();
  // phase 2: numerator = prefix part + intra part
  const int s = t >> 2, dg = t & 3;
  const float* kvp = KVc + ((size_t)(h * NC_ + c)) * MF_ * DH_;
  float num[16];
#pragma unroll
  for (int i = 0; i < 16; ++i) num[i] = 0.f;
  for (int m = 0; m < MF_; ++m) {
    float p = pq[s][m];
    const float* kr = kvp + m * DH_ + dg * 16;
#pragma unroll
    for (int i = 0; i < 16; ++i) num[i] += p * kr[i];
  }
  for (int tt = 0; tt <= s; ++tt) {
    float w = Tm[s][tt];
    const float* vr = &pkv[tt][dg * 16];
#pragma unroll
    for (int i = 0; i < 16; ++i) num[i] += w * vr[i];
  }
  const float inv = 1.f / den[s];
  float* outp = Aout + (size_t)(c * CT_ + s) * DM_ + h * DH_ + dg * 16;
#pragma unroll
  for (int i = 0; i < 16; ++i) outp[i] = num[i] * inv;
}

// ---------------------------------------------------------------- LayerNorm
__global__ __launch_bounds__(256) void ln_kernel(const float* __restrict__ X,
                                                 const float* __restrict__ g,
                                                 const float* __restrict__ be,
                                                 float* __restrict__ outF) {
  const int s = blockIdx.x, t = threadIdx.x;
  float v0 = X[(size_t)s * DM_ + t];
  float v1 = X[(size_t)s * DM_ + 256 + t];
  float sum = v0 + v1, sq = v0 * v0 + v1 * v1;
  for (int off = 32; off > 0; off >>= 1) {
    sum += __shfl_down(sum, off);
    sq += __shfl_down(sq, off);
  }
  __shared__ float ssum[4], ssq[4];
  __shared__ float smean, srstd;
  const int w = t >> 6;
  if ((t & 63) == 0) { ssum[w] = sum; ssq[w] = sq; }
  __syncthreads();
  if (t == 0) {
    float S1 = ssum[0] + ssum[1] + ssum[2] + ssum[3];
    float S2 = ssq[0] + ssq[1] + ssq[2] + ssq[3];
    float mu = S1 / DM_;
    float var = S2 / DM_ - mu * mu;
    smean = mu;
    srstd = rsqrtf(var + LN_EPS_);
  }
  __syncthreads();
  const float mu = smean, rs = srstd;
  outF[(size_t)s * DM_ + t] = (v0 - mu) * rs * g[t] + be[t];
  outF[(size_t)s * DM_ + 256 + t] = (v1 - mu) * rs * g[256 + t] + be[256 + t];
}

// ---------------------------------------------------------------- launch
extern "C" void kernel_launch(void* const* d_in, const int* in_sizes, int n_in,
                              void* d_out, int out_size, void* d_ws, size_t ws_size,
                              hipStream_t stream) {
  const float* x    = (const float*)d_in[0];
  const float* Wq   = (const float*)d_in[1];
  const float* Wk   = (const float*)d_in[2];
  const float* Wv   = (const float*)d_in[3];
  const float* Wo   = (const float*)d_in[4];
  const float* W1   = (const float*)d_in[5];
  const float* W2   = (const float*)d_in[6];
  const float* bq   = (const float*)d_in[7];
  const float* bk   = (const float*)d_in[8];
  const float* bv   = (const float*)d_in[9];
  const float* bo   = (const float*)d_in[10];
  const float* b1   = (const float*)d_in[11];
  const float* b2   = (const float*)d_in[12];
  const float* g1   = (const float*)d_in[13];
  const float* be1  = (const float*)d_in[14];
  const float* g2   = (const float*)d_in[15];
  const float* be2  = (const float*)d_in[16];
  const float* omg  = (const float*)d_in[17];
  float* out = (float*)d_out;

  float* ws   = (float*)d_ws;
  float* cur  = ws;                      // [S,DM]
  float* qb   = cur + (size_t)S_ * DM_;  // [S,DM]  (also reused as attn output)
  float* kb   = qb + (size_t)S_ * DM_;
  float* vb   = kb + (size_t)S_ * DM_;
  float* pqb  = vb + (size_t)S_ * DM_;
  float* pkb  = pqb + (size_t)S_ * DM_;
  float* ln1  = pkb + (size_t)S_ * DM_;
  float* tmp1 = ln1 + (size_t)S_ * DM_;
  float* ff   = tmp1 + (size_t)S_ * DM_;             // [S,DFF]
  float* KVcb = ff + (size_t)S_ * DFF_;              // [H,NC,M,DH]
  float* Kcb  = KVcb + (size_t)H_ * NC_ * MF_ * DH_; // [H,NC,M]

  copy_kernel<<<S_ * DM_ / 256, 256, 0, stream>>>(x, cur);

  const dim3 g512(DM_ / 64, S_ / 64);    // (8,32)
  const dim3 gFF1(DFF_ / 64, S_ / 64);   // (32,32)
  const dim3 gAttn(NC_, H_);             // (32,8)

  for (int l = 0; l < L_; ++l) {
    const size_t wo = (size_t)l * DM_ * DM_;
    const size_t w1o = (size_t)l * DM_ * DFF_;
    const size_t w2o = (size_t)l * DFF_ * DM_;
    const size_t bo512 = (size_t)l * DM_;
    const size_t boFF = (size_t)l * DFF_;
    const size_t omo = (size_t)l * DH_ * MF_;

    gemm_kernel<false, false><<<g512, 256, 0, stream>>>(cur, Wq + wo, bq + bo512, nullptr, qb, DM_, DM_);
    gemm_kernel<false, false><<<g512, 256, 0, stream>>>(cur, Wk + wo, bk + bo512, nullptr, kb, DM_, DM_);
    gemm_kernel<false, false><<<g512, 256, 0, stream>>>(cur, Wv + wo, bv + bo512, nullptr, vb, DM_, DM_);

    favor_kernel<<<S_, 512, 0, stream>>>(qb, omg + omo, pqb);
    favor_kernel<<<S_, 512, 0, stream>>>(kb, omg + omo, pkb);

    chunk_sums<<<gAttn, 256, 0, stream>>>(pkb, vb, KVcb, Kcb);
    prefix_kernel<<<H_, 256, 0, stream>>>(KVcb, Kcb);
    attn_out<<<gAttn, 256, 0, stream>>>(pqb, pkb, vb, KVcb, Kcb, qb);  // qb := attn result

    gemm_kernel<false, true><<<g512, 256, 0, stream>>>(qb, Wo + wo, bo + bo512, cur, tmp1, DM_, DM_);
    ln_kernel<<<S_, 256, 0, stream>>>(tmp1, g1 + bo512, be1 + bo512, ln1);

    gemm_kernel<true, false><<<gFF1, 256, 0, stream>>>(ln1, W1 + w1o, b1 + boFF, nullptr, ff, DM_, DFF_);
    gemm_kernel<false, true><<<g512, 256, 0, stream>>>(ff, W2 + w2o, b2 + bo512, ln1, tmp1, DFF_, DM_);

    const bool last = (l == L_ - 1);
    ln_kernel<<<S_, 256, 0, stream>>>(tmp1, g2 + bo512, be2 + bo512,
                                      last ? out : cur);
  }
}

// Round 3
// 428.030 us; speedup vs baseline: 2.1884x; 2.1884x over previous
//
#include <hip/hip_runtime.h>
#include <hip/hip_bf16.h>

#define S_  2048
#define DM_ 512
#define H_  8
#define DH_ 64
#define MF_ 64
#define DFF_ 2048
#define L_  2
#define CT_ 64
#define NC_ (S_ / CT_)
#define EPS_ 1e-6f
#define LN_EPS_ 1e-5f

typedef unsigned short ushortT;
typedef float f4 __attribute__((ext_vector_type(4)));
typedef short s8 __attribute__((ext_vector_type(8)));

__device__ __forceinline__ ushortT f2b(float f) {
  union { float f; unsigned u; } v; v.f = f;
  unsigned r = v.u + 0x7fffu + ((v.u >> 16) & 1u);  // RNE
  return (ushortT)(r >> 16);
}

// ---------------------------------------------------------------- copy in
__global__ __launch_bounds__(256) void copy_in(const float* __restrict__ x,
                                               float* __restrict__ cur,
                                               ushortT* __restrict__ curb) {
  int i = blockIdx.x * 256 + threadIdx.x;
  float v = x[i];
  cur[i] = v;
  curb[i] = f2b(v);
}

// ---------------------------------------------------------------- weight transpose+cast
// src fp32 [K][N] -> dst bf16 [N][K]
struct P4 { const float* p[4]; };
__global__ __launch_bounds__(256) void tcast(P4 srcs, int perLayer, int nper,
                                             ushortT* __restrict__ dstb,
                                             size_t layerStride, size_t wStride,
                                             int K, int N) {
  const int z = blockIdx.z;
  const int widx = (nper == 4) ? (z & 3) : 0;
  const int l = (nper == 4) ? (z >> 2) : z;
  const float* src = srcs.p[widx] + (size_t)l * perLayer;
  ushortT* dst = dstb + (size_t)l * layerStride + (size_t)widx * wStride;
  __shared__ ushortT tile[32][33];
  const int t = threadIdx.x;
  const int c = t & 31, r0 = t >> 5;
  const int n0 = blockIdx.x * 32, k0 = blockIdx.y * 32;
#pragma unroll
  for (int i = 0; i < 4; ++i) {
    int r = r0 + 8 * i;
    tile[r][c] = f2b(src[(size_t)(k0 + r) * N + n0 + c]);
  }
  __syncthreads();
#pragma unroll
  for (int i = 0; i < 4; ++i) {
    int r = r0 + 8 * i;
    dst[(size_t)(n0 + r) * K + k0 + c] = tile[c][r];
  }
}

// ---------------------------------------------------------------- MFMA GEMM
// C[M=S_, N] = act(A[M,K](bf16) @ Wt[N,K]^T(bf16) + bias (+ Res)); out fp32 or bf16.
// 64x64 block tile, 4 waves of 32x32, BK=32, double-buffered LDS via
// global_load_lds(16B) with XOR-swizzled granule placement (conflict-free b128 reads).
// blockIdx.z selects {W,bias,out} slice (QKV fusion); z=0 otherwise.
template<bool RELU, bool HAS_RES, bool OUT_BF16>
__global__ __launch_bounds__(256) void mgemm(
    const ushortT* __restrict__ A, const ushortT* __restrict__ Wt,
    const float* __restrict__ bq_, const float* __restrict__ bk_,
    const float* __restrict__ bv_, const float* __restrict__ Res,
    float* __restrict__ Cf, ushortT* __restrict__ Cb, int K, int N) {
  __shared__ ushortT sA[2][2048];
  __shared__ ushortT sB[2][2048];
  const int t = threadIdx.x;
  const int w = t >> 6, l = t & 63;
  const int wm = w >> 1, wn = w & 1;
  const int n0 = blockIdx.x * 64, m0 = blockIdx.y * 64;
  const int z = blockIdx.z;
  const ushortT* Wz = Wt + (size_t)z * K * N;
  const float* bias = (z == 0) ? bq_ : (z == 1 ? bk_ : bv_);

  // staging: wave w covers tile rows [w*16, w*16+16); lane l -> row rs, phys granule l&3,
  // fetches global k-quad qs = (l&3) ^ swizzle(rs)
  const int rs = w * 16 + (l >> 2);
  const int qs = (l & 3) ^ ((rs >> 1) & 3);
  const ushortT* gA = A  + (size_t)(m0 + rs) * K + qs * 8;
  const ushortT* gB = Wz + (size_t)(n0 + rs) * K + qs * 8;

  // frag-read byte offsets (in ushorts): logical (row R, kquad qq) -> granule R*4 + (qq^sw(R))
  const int Ra = wm * 32 + (l & 15);
  const int Rb = wn * 32 + (l & 15);
  const int qq = l >> 4;
  const int aoff = (Ra * 4 + (qq ^ ((Ra >> 1) & 3))) * 8;
  const int boff = (Rb * 4 + (qq ^ ((Rb >> 1) & 3))) * 8;

  f4 acc[2][2];
#pragma unroll
  for (int i = 0; i < 2; ++i)
#pragma unroll
    for (int j = 0; j < 2; ++j) acc[i][j] = (f4){0.f, 0.f, 0.f, 0.f};

  auto stage = [&](int buf, int ko) {
    __builtin_amdgcn_global_load_lds(
        (const __attribute__((address_space(1))) void*)(gA + ko),
        (__attribute__((address_space(3))) void*)(&sA[buf][w * 512]), 16, 0, 0);
    __builtin_amdgcn_global_load_lds(
        (const __attribute__((address_space(1))) void*)(gB + ko),
        (__attribute__((address_space(3))) void*)(&sB[buf][w * 512]), 16, 0, 0);
  };

  stage(0, 0);
  const int nk = K >> 5;
  for (int ks = 0; ks < nk; ++ks) {
    __syncthreads();  // staged data visible (barrier drains vmcnt); prior reads of other buf done
    if (ks + 1 < nk) stage((ks + 1) & 1, (ks + 1) * 32);
    const ushortT* pa = sA[ks & 1];
    const ushortT* pb = sB[ks & 1];
    s8 a0 = *(const s8*)(pa + aoff);
    s8 a1 = *(const s8*)(pa + aoff + 512);
    s8 b0 = *(const s8*)(pb + boff);
    s8 b1 = *(const s8*)(pb + boff + 512);
    acc[0][0] = __builtin_amdgcn_mfma_f32_16x16x32_bf16(a0, b0, acc[0][0], 0, 0, 0);
    acc[0][1] = __builtin_amdgcn_mfma_f32_16x16x32_bf16(a0, b1, acc[0][1], 0, 0, 0);
    acc[1][0] = __builtin_amdgcn_mfma_f32_16x16x32_bf16(a1, b0, acc[1][0], 0, 0, 0);
    acc[1][1] = __builtin_amdgcn_mfma_f32_16x16x32_bf16(a1, b1, acc[1][1], 0, 0, 0);
  }

  // epilogue: D row=(l>>4)*4+reg, col=l&15 (m89-verified)
  const size_t outz = (size_t)z * S_ * N;
  const int colb = n0 + wn * 32 + (l & 15);
  const int rowb = m0 + wm * 32 + ((l >> 4) << 2);
#pragma unroll
  for (int mt = 0; mt < 2; ++mt) {
#pragma unroll
    for (int nt = 0; nt < 2; ++nt) {
      const int c = colb + nt * 16;
      const float bv = bias[c];
#pragma unroll
      for (int r = 0; r < 4; ++r) {
        const int rr = rowb + mt * 16 + r;
        float v = acc[mt][nt][r] + bv;
        if (HAS_RES) v += Res[(size_t)rr * N + c];
        if (RELU) v = fmaxf(v, 0.f);
        if (OUT_BF16) Cb[outz + (size_t)rr * N + c] = f2b(v);
        else          Cf[outz + (size_t)rr * N + c] = v;
      }
    }
  }
}

// ---------------------------------------------------------------- FAVOR+ (fused q/k)
__global__ __launch_bounds__(512) void favor2(const float* __restrict__ qsrc,
                                              const float* __restrict__ ksrc,
                                              const float* __restrict__ omega,
                                              float* __restrict__ pqd,
                                              float* __restrict__ pkd) {
  const float* src = blockIdx.y ? ksrc : qsrc;
  float* dst = blockIdx.y ? pkd : pqd;
  __shared__ float qs[DM_];
  __shared__ float om[DH_ * MF_];
  const int t = threadIdx.x, s = blockIdx.x;
  qs[t] = src[(size_t)s * DM_ + t] * 0.35355339059327373f;  // 64^-0.25
  for (int i = t; i < DH_ * MF_; i += 512) om[i] = omega[i];
  __syncthreads();
  const int h = t >> 6, m = t & 63;
  const float* qh = qs + h * DH_;
  float nrm = 0.f, u = 0.f;
#pragma unroll 8
  for (int d = 0; d < DH_; ++d) {
    float x = qh[d];
    nrm += x * x;
    u += x * om[d * MF_ + m];
  }
  dst[(size_t)s * DM_ + t] = expf(u - 0.5f * nrm) * 0.125f;  // 64^-0.5
}

// ---------------------------------------------------------------- chunk sums
__global__ __launch_bounds__(256) void chunk_sums(const float* __restrict__ PK,
                                                  const float* __restrict__ V,
                                                  float* __restrict__ KVc,
                                                  float* __restrict__ Kc) {
  const int c = blockIdx.x, h = blockIdx.y, t = threadIdx.x;
  __shared__ float pk[CT_][MF_];
  __shared__ float vs[CT_][DH_];
  for (int i = t; i < CT_ * MF_; i += 256) {
    int tt = i >> 6, m = i & 63;
    pk[tt][m] = PK[(size_t)(c * CT_ + tt) * DM_ + h * MF_ + m];
    vs[tt][m] = V[(size_t)(c * CT_ + tt) * DM_ + h * DH_ + m];
  }
  __syncthreads();
  const int m = t >> 2, dg = t & 3;
  float acc[16];
#pragma unroll
  for (int i = 0; i < 16; ++i) acc[i] = 0.f;
  float ks = 0.f;
  for (int tt = 0; tt < CT_; ++tt) {
    float p = pk[tt][m];
    ks += p;
    const float* vr = &vs[tt][dg * 16];
#pragma unroll
    for (int i = 0; i < 16; ++i) acc[i] += p * vr[i];
  }
  float* kvout = KVc + ((size_t)(h * NC_ + c)) * MF_ * DH_ + m * DH_ + dg * 16;
#pragma unroll
  for (int i = 0; i < 16; ++i) kvout[i] = acc[i];
  if (dg == 0) Kc[(size_t)(h * NC_ + c) * MF_ + m] = ks;
}

// ---------------------------------------------------------------- prefix scan
__global__ __launch_bounds__(256) void prefix_kernel(float* __restrict__ KVc,
                                                     float* __restrict__ Kc) {
  const int h = blockIdx.x, t = threadIdx.x;
  for (int e = t; e < MF_ * DH_; e += 256) {
    float run = 0.f;
    for (int c = 0; c < NC_; ++c) {
      float* p = KVc + ((size_t)(h * NC_ + c)) * MF_ * DH_ + e;
      float tmp = *p; *p = run; run += tmp;
    }
  }
  if (t < MF_) {
    float run = 0.f;
    for (int c = 0; c < NC_; ++c) {
      float* p = Kc + (size_t)(h * NC_ + c) * MF_ + t;
      float tmp = *p; *p = run; run += tmp;
    }
  }
}

// ---------------------------------------------------------------- attention out (bf16 out)
__global__ __launch_bounds__(256) void attn_out(const float* __restrict__ PQ,
                                                const float* __restrict__ PK,
                                                const float* __restrict__ V,
                                                const float* __restrict__ KVc,
                                                const float* __restrict__ Kc,
                                                ushortT* __restrict__ Aout) {
  const int c = blockIdx.x, h = blockIdx.y, t = threadIdx.x;
  __shared__ float pq[CT_][MF_ + 1];
  __shared__ float pkv[CT_][MF_ + 1];
  __shared__ float Tm[CT_][CT_ + 1];
  __shared__ float den[CT_];

  for (int i = t; i < CT_ * MF_; i += 256) {
    int s = i >> 6, m = i & 63;
    pq[s][m] = PQ[(size_t)(c * CT_ + s) * DM_ + h * MF_ + m];
    pkv[s][m] = PK[(size_t)(c * CT_ + s) * DM_ + h * MF_ + m];
  }
  __syncthreads();
  for (int i = t; i < CT_ * CT_; i += 256) {
    int s = i >> 6, tt = i & 63;
    float d = 0.f;
    if (tt <= s) {
#pragma unroll 8
      for (int m = 0; m < MF_; ++m) d += pq[s][m] * pkv[tt][m];
    }
    Tm[s][tt] = d;
  }
  __syncthreads();
  if (t < CT_) {
    const int s = t;
    float d = EPS_;
    const float* kc = Kc + (size_t)(h * NC_ + c) * MF_;
    for (int m = 0; m < MF_; ++m) d += pq[s][m] * kc[m];
    for (int tt = 0; tt <= s; ++tt) d += Tm[s][tt];
    den[s] = d;
  }
  for (int i = t; i < CT_ * MF_; i += 256) {
    int s = i >> 6, m = i & 63;
    pkv[s][m] = V[(size_t)(c * CT_ + s) * DM_ + h * DH_ + m];
  }
  __syncthreads();
  const int s = t >> 2, dg = t & 3;
  const float* kvp = KVc + ((size_t)(h * NC_ + c)) * MF_ * DH_;
  float num[16];
#pragma unroll
  for (int i = 0; i < 16; ++i) num[i] = 0.f;
  for (int m = 0; m < MF_; ++m) {
    float p = pq[s][m];
    const float* kr = kvp + m * DH_ + dg * 16;
#pragma unroll
    for (int i = 0; i < 16; ++i) num[i] += p * kr[i];
  }
  for (int tt = 0; tt <= s; ++tt) {
    float w = Tm[s][tt];
    const float* vr = &pkv[tt][dg * 16];
#pragma unroll
    for (int i = 0; i < 16; ++i) num[i] += w * vr[i];
  }
  const float inv = 1.f / den[s];
  ushortT* outp = Aout + (size_t)(c * CT_ + s) * DM_ + h * DH_ + dg * 16;
#pragma unroll
  for (int i = 0; i < 16; ++i) outp[i] = f2b(num[i] * inv);
}

// ---------------------------------------------------------------- LayerNorm (dual out)
__global__ __launch_bounds__(256) void ln_kernel(const float* __restrict__ X,
                                                 const float* __restrict__ g,
                                                 const float* __restrict__ be,
                                                 float* __restrict__ outF,
                                                 ushortT* __restrict__ outB) {
  const int s = blockIdx.x, t = threadIdx.x;
  float v0 = X[(size_t)s * DM_ + t];
  float v1 = X[(size_t)s * DM_ + 256 + t];
  float sum = v0 + v1, sq = v0 * v0 + v1 * v1;
  for (int off = 32; off > 0; off >>= 1) {
    sum += __shfl_down(sum, off);
    sq += __shfl_down(sq, off);
  }
  __shared__ float ssum[4], ssq[4];
  __shared__ float smean, srstd;
  const int w = t >> 6;
  if ((t & 63) == 0) { ssum[w] = sum; ssq[w] = sq; }
  __syncthreads();
  if (t == 0) {
    float S1 = ssum[0] + ssum[1] + ssum[2] + ssum[3];
    float S2 = ssq[0] + ssq[1] + ssq[2] + ssq[3];
    float mu = S1 / DM_;
    float var = S2 / DM_ - mu * mu;
    smean = mu;
    srstd = rsqrtf(var + LN_EPS_);
  }
  __syncthreads();
  const float mu = smean, rs = srstd;
  float o0 = (v0 - mu) * rs * g[t] + be[t];
  float o1 = (v1 - mu) * rs * g[256 + t] + be[256 + t];
  outF[(size_t)s * DM_ + t] = o0;
  outF[(size_t)s * DM_ + 256 + t] = o1;
  if (outB) {
    outB[(size_t)s * DM_ + t] = f2b(o0);
    outB[(size_t)s * DM_ + 256 + t] = f2b(o1);
  }
}

// ---------------------------------------------------------------- launch
extern "C" void kernel_launch(void* const* d_in, const int* in_sizes, int n_in,
                              void* d_out, int out_size, void* d_ws, size_t ws_size,
                              hipStream_t stream) {
  const float* x    = (const float*)d_in[0];
  const float* Wq   = (const float*)d_in[1];
  const float* Wk   = (const float*)d_in[2];
  const float* Wv   = (const float*)d_in[3];
  const float* Wo   = (const float*)d_in[4];
  const float* W1   = (const float*)d_in[5];
  const float* W2   = (const float*)d_in[6];
  const float* bq   = (const float*)d_in[7];
  const float* bk   = (const float*)d_in[8];
  const float* bv   = (const float*)d_in[9];
  const float* bo   = (const float*)d_in[10];
  const float* b1   = (const float*)d_in[11];
  const float* b2   = (const float*)d_in[12];
  const float* g1   = (const float*)d_in[13];
  const float* be1  = (const float*)d_in[14];
  const float* g2   = (const float*)d_in[15];
  const float* be2  = (const float*)d_in[16];
  const float* omg  = (const float*)d_in[17];
  float* out = (float*)d_out;

  const size_t MB = 1048576;  // 1M elems
  float* f    = (float*)d_ws;
  float* cur  = f;            // [S,DM] fp32
  float* qb   = f + 1 * MB;   // q fp32 (favor input); QKV z-out base
  float* kb   = f + 2 * MB;   // k fp32; later aliased as tmp1
  float* vb   = f + 3 * MB;   // v fp32
  float* pqb  = f + 4 * MB;   // phi(q); [pqb,pkb] later aliased as ffb (bf16)
  float* pkb  = f + 5 * MB;
  float* ln1  = f + 6 * MB;
  float* KVcb = f + 7 * MB;                 // [H,NC,M,DH] = 1M
  float* Kcb  = f + 8 * MB;                 // [H,NC,M] = 16K
  float* tmp1 = kb;                         // alias: k dead after favor2
  ushortT* u  = (ushortT*)(f + 8 * MB + 16384);
  ushortT* curb = u;            // [S,DM] bf16
  ushortT* qbb  = u + 1 * MB;   // attn output bf16
  ushortT* ln1b = u + 2 * MB;   // ln1 bf16
  ushortT* wb   = u + 3 * MB;   // transposed bf16 weights
  ushortT* ffb  = (ushortT*)pqb;  // [S,DFF] bf16 = 4M ushorts over pqb+pkb

  const size_t LS = 3145728;  // per-layer ushorts in wb
  const size_t W1OFF = 1048576, W2OFF = 2097152, WOOFF = 786432;

  copy_in<<<S_ * DM_ / 256, 256, 0, stream>>>(x, cur, curb);

  {  // weight transpose+cast (every call; graph-safe)
    P4 s4; s4.p[0] = Wq; s4.p[1] = Wk; s4.p[2] = Wv; s4.p[3] = Wo;
    tcast<<<dim3(16, 16, 8), 256, 0, stream>>>(s4, DM_ * DM_, 4, wb, LS, DM_ * DM_, DM_, DM_);
    P4 s1; s1.p[0] = W1; s1.p[1] = W1; s1.p[2] = W1; s1.p[3] = W1;
    tcast<<<dim3(64, 16, 2), 256, 0, stream>>>(s1, DM_ * DFF_, 1, wb + W1OFF, LS, 0, DM_, DFF_);
    P4 s2; s2.p[0] = W2; s2.p[1] = W2; s2.p[2] = W2; s2.p[3] = W2;
    tcast<<<dim3(16, 64, 2), 256, 0, stream>>>(s2, DFF_ * DM_, 1, wb + W2OFF, LS, 0, DFF_, DM_);
  }

  const dim3 gQKV(DM_ / 64, S_ / 64, 3);   // (8,32,3)
  const dim3 g512(DM_ / 64, S_ / 64, 1);   // (8,32)
  const dim3 gFF1(DFF_ / 64, S_ / 64, 1);  // (32,32)
  const dim3 gAttn(NC_, H_);

  for (int l = 0; l < L_; ++l) {
    const ushortT* wl = wb + (size_t)l * LS;
    const size_t bo512 = (size_t)l * DM_;
    const size_t boFF = (size_t)l * DFF_;

    mgemm<false, false, false><<<gQKV, 256, 0, stream>>>(
        curb, wl, bq + bo512, bk + bo512, bv + bo512, nullptr, qb, nullptr, DM_, DM_);

    favor2<<<dim3(S_, 2), 512, 0, stream>>>(qb, kb, omg + (size_t)l * DH_ * MF_, pqb, pkb);
    chunk_sums<<<gAttn, 256, 0, stream>>>(pkb, vb, KVcb, Kcb);
    prefix_kernel<<<H_, 256, 0, stream>>>(KVcb, Kcb);
    attn_out<<<gAttn, 256, 0, stream>>>(pqb, pkb, vb, KVcb, Kcb, qbb);

    mgemm<false, true, false><<<g512, 256, 0, stream>>>(
        qbb, wl + WOOFF, bo + bo512, nullptr, nullptr, cur, tmp1, nullptr, DM_, DM_);
    ln_kernel<<<S_, 256, 0, stream>>>(tmp1, g1 + bo512, be1 + bo512, ln1, ln1b);

    mgemm<true, false, true><<<gFF1, 256, 0, stream>>>(
        ln1b, wl + W1OFF, b1 + boFF, nullptr, nullptr, nullptr, nullptr, ffb, DM_, DFF_);
    mgemm<false, true, false><<<g512, 256, 0, stream>>>(
        ffb, wl + W2OFF, b2 + bo512, nullptr, nullptr, ln1, tmp1, nullptr, DFF_, DM_);

    const bool last = (l == L_ - 1);
    ln_kernel<<<S_, 256, 0, stream>>>(tmp1, g2 + bo512, be2 + bo512,
                                      last ? out : cur, last ? nullptr : curb);
  }
}

// Round 4
// 361.210 us; speedup vs baseline: 2.5933x; 1.1850x over previous
//
#include <hip/hip_runtime.h>
#include <hip/hip_bf16.h>

#define S_  2048
#define DM_ 512
#define H_  8
#define DH_ 64
#define MF_ 64
#define DFF_ 2048
#define L_  2
#define CT_ 64
#define NC_ (S_ / CT_)
#define EPS_ 1e-6f
#define LN_EPS_ 1e-5f

typedef unsigned short ushortT;
typedef unsigned int u32;
typedef float f4 __attribute__((ext_vector_type(4)));
typedef short s8 __attribute__((ext_vector_type(8)));
typedef u32 u32x2 __attribute__((ext_vector_type(2)));

__device__ __forceinline__ ushortT f2b(float f) {
  union { float f; unsigned u; } v; v.f = f;
  unsigned r = v.u + 0x7fffu + ((v.u >> 16) & 1u);  // RNE
  return (ushortT)(r >> 16);
}
__device__ __forceinline__ float bu2f(ushortT h) {
  union { unsigned u; float f; } v; v.u = ((unsigned)h) << 16; return v.f;
}
__device__ __forceinline__ u32 pk2(float a, float b) {
  return (u32)f2b(a) | ((u32)f2b(b) << 16);
}

// ---------------------------------------------------------------- copy in
__global__ __launch_bounds__(256) void copy_in(const float* __restrict__ x,
                                               float* __restrict__ cur,
                                               ushortT* __restrict__ curb) {
  int i = blockIdx.x * 256 + threadIdx.x;
  float v = x[i];
  cur[i] = v;
  curb[i] = f2b(v);
}

// ---------------------------------------------------------------- weight transpose+cast
struct P4 { const float* p[4]; };
__global__ __launch_bounds__(256) void tcast(P4 srcs, int perLayer, int nper,
                                             ushortT* __restrict__ dstb,
                                             size_t layerStride, size_t wStride,
                                             int K, int N) {
  const int z = blockIdx.z;
  const int widx = (nper == 4) ? (z & 3) : 0;
  const int l = (nper == 4) ? (z >> 2) : z;
  const float* src = srcs.p[widx] + (size_t)l * perLayer;
  ushortT* dst = dstb + (size_t)l * layerStride + (size_t)widx * wStride;
  __shared__ ushortT tile[32][33];
  const int t = threadIdx.x;
  const int c = t & 31, r0 = t >> 5;
  const int n0 = blockIdx.x * 32, k0 = blockIdx.y * 32;
#pragma unroll
  for (int i = 0; i < 4; ++i) {
    int r = r0 + 8 * i;
    tile[r][c] = f2b(src[(size_t)(k0 + r) * N + n0 + c]);
  }
  __syncthreads();
#pragma unroll
  for (int i = 0; i < 4; ++i) {
    int r = r0 + 8 * i;
    dst[(size_t)(n0 + r) * K + k0 + c] = tile[c][r];
  }
}

// ---------------------------------------------------------------- MFMA GEMM (unchanged from R3)
template<bool RELU, bool HAS_RES, bool OUT_BF16>
__global__ __launch_bounds__(256) void mgemm(
    const ushortT* __restrict__ A, const ushortT* __restrict__ Wt,
    const float* __restrict__ bq_, const float* __restrict__ bk_,
    const float* __restrict__ bv_, const float* __restrict__ Res,
    float* __restrict__ Cf, ushortT* __restrict__ Cb, int K, int N) {
  __shared__ ushortT sA[2][2048];
  __shared__ ushortT sB[2][2048];
  const int t = threadIdx.x;
  const int w = t >> 6, l = t & 63;
  const int wm = w >> 1, wn = w & 1;
  const int n0 = blockIdx.x * 64, m0 = blockIdx.y * 64;
  const int z = blockIdx.z;
  const ushortT* Wz = Wt + (size_t)z * K * N;
  const float* bias = (z == 0) ? bq_ : (z == 1 ? bk_ : bv_);

  const int rs = w * 16 + (l >> 2);
  const int qs = (l & 3) ^ ((rs >> 1) & 3);
  const ushortT* gA = A  + (size_t)(m0 + rs) * K + qs * 8;
  const ushortT* gB = Wz + (size_t)(n0 + rs) * K + qs * 8;

  const int Ra = wm * 32 + (l & 15);
  const int Rb = wn * 32 + (l & 15);
  const int qq = l >> 4;
  const int aoff = (Ra * 4 + (qq ^ ((Ra >> 1) & 3))) * 8;
  const int boff = (Rb * 4 + (qq ^ ((Rb >> 1) & 3))) * 8;

  f4 acc[2][2];
#pragma unroll
  for (int i = 0; i < 2; ++i)
#pragma unroll
    for (int j = 0; j < 2; ++j) acc[i][j] = (f4){0.f, 0.f, 0.f, 0.f};

  auto stage = [&](int buf, int ko) {
    __builtin_amdgcn_global_load_lds(
        (const __attribute__((address_space(1))) void*)(gA + ko),
        (__attribute__((address_space(3))) void*)(&sA[buf][w * 512]), 16, 0, 0);
    __builtin_amdgcn_global_load_lds(
        (const __attribute__((address_space(1))) void*)(gB + ko),
        (__attribute__((address_space(3))) void*)(&sB[buf][w * 512]), 16, 0, 0);
  };

  stage(0, 0);
  const int nk = K >> 5;
  for (int ks = 0; ks < nk; ++ks) {
    __syncthreads();
    if (ks + 1 < nk) stage((ks + 1) & 1, (ks + 1) * 32);
    const ushortT* pa = sA[ks & 1];
    const ushortT* pb = sB[ks & 1];
    s8 a0 = *(const s8*)(pa + aoff);
    s8 a1 = *(const s8*)(pa + aoff + 512);
    s8 b0 = *(const s8*)(pb + boff);
    s8 b1 = *(const s8*)(pb + boff + 512);
    acc[0][0] = __builtin_amdgcn_mfma_f32_16x16x32_bf16(a0, b0, acc[0][0], 0, 0, 0);
    acc[0][1] = __builtin_amdgcn_mfma_f32_16x16x32_bf16(a0, b1, acc[0][1], 0, 0, 0);
    acc[1][0] = __builtin_amdgcn_mfma_f32_16x16x32_bf16(a1, b0, acc[1][0], 0, 0, 0);
    acc[1][1] = __builtin_amdgcn_mfma_f32_16x16x32_bf16(a1, b1, acc[1][1], 0, 0, 0);
  }

  const size_t outz = (size_t)z * S_ * N;
  const int colb = n0 + wn * 32 + (l & 15);
  const int rowb = m0 + wm * 32 + ((l >> 4) << 2);
#pragma unroll
  for (int mt = 0; mt < 2; ++mt) {
#pragma unroll
    for (int nt = 0; nt < 2; ++nt) {
      const int c = colb + nt * 16;
      const float bv = bias[c];
#pragma unroll
      for (int r = 0; r < 4; ++r) {
        const int rr = rowb + mt * 16 + r;
        float v = acc[mt][nt][r] + bv;
        if (HAS_RES) v += Res[(size_t)rr * N + c];
        if (RELU) v = fmaxf(v, 0.f);
        if (OUT_BF16) Cb[outz + (size_t)rr * N + c] = f2b(v);
        else          Cf[outz + (size_t)rr * N + c] = v;
      }
    }
  }
}

// ---------------------------------------------------------------- FAVOR+ (fused q/k)
__global__ __launch_bounds__(512) void favor2(const float* __restrict__ qsrc,
                                              const float* __restrict__ ksrc,
                                              const float* __restrict__ omega,
                                              float* __restrict__ pqd,
                                              float* __restrict__ pkd) {
  const float* src = blockIdx.y ? ksrc : qsrc;
  float* dst = blockIdx.y ? pkd : pqd;
  __shared__ float qs[DM_];
  __shared__ float om[DH_ * MF_];
  const int t = threadIdx.x, s = blockIdx.x;
  qs[t] = src[(size_t)s * DM_ + t] * 0.35355339059327373f;  // 64^-0.25
  for (int i = t; i < DH_ * MF_; i += 512) om[i] = omega[i];
  __syncthreads();
  const int h = t >> 6, m = t & 63;
  const float* qh = qs + h * DH_;
  float nrm = 0.f, u = 0.f;
#pragma unroll 8
  for (int d = 0; d < DH_; ++d) {
    float x = qh[d];
    nrm += x * x;
    u += x * om[d * MF_ + m];
  }
  dst[(size_t)s * DM_ + t] = expf(u - 0.5f * nrm) * 0.125f;  // 64^-0.5
}

// ---------------------------------------------------------------- chunk sums (TRANSPOSED out)
// KVcT[h][c][d][m] = sum_t pk[t,m] v[t,d];  Kc[h][c][m] = sum_t pk[t,m]
__global__ __launch_bounds__(256) void chunk_sums(const float* __restrict__ PK,
                                                  const float* __restrict__ V,
                                                  float* __restrict__ KVcT,
                                                  float* __restrict__ Kc) {
  const int c = blockIdx.x, h = blockIdx.y, t = threadIdx.x;
  __shared__ float pk[CT_][MF_];
  __shared__ float vs[CT_][DH_];
  for (int i = t; i < CT_ * MF_ / 4; i += 256) {
    int tt = i >> 4, m4 = i & 15;
    ((f4*)pk)[tt * 16 + m4] = *(const f4*)(PK + (size_t)(c * CT_ + tt) * DM_ + h * MF_ + m4 * 4);
    ((f4*)vs)[tt * 16 + m4] = *(const f4*)(V  + (size_t)(c * CT_ + tt) * DM_ + h * DH_ + m4 * 4);
  }
  __syncthreads();
  const int d = t >> 2, mg = t & 3;
  float acc[16];
#pragma unroll
  for (int i = 0; i < 16; ++i) acc[i] = 0.f;
  for (int tt = 0; tt < CT_; ++tt) {
    float v = vs[tt][d];
    const f4* pr = (const f4*)&pk[tt][mg * 16];
#pragma unroll
    for (int j = 0; j < 4; ++j) {
      f4 p = pr[j];
      acc[4 * j + 0] += v * p.x;
      acc[4 * j + 1] += v * p.y;
      acc[4 * j + 2] += v * p.z;
      acc[4 * j + 3] += v * p.w;
    }
  }
  float* outp = KVcT + ((size_t)(h * NC_ + c) * DH_ + d) * MF_ + mg * 16;
#pragma unroll
  for (int i = 0; i < 16; ++i) outp[i] = acc[i];
  if (t < MF_) {
    float ks = 0.f;
    for (int tt = 0; tt < CT_; ++tt) ks += pk[tt][t];
    Kc[(size_t)(h * NC_ + c) * MF_ + t] = ks;
  }
}

// ---------------------------------------------------------------- prefix scan (exclusive, per head)
__global__ __launch_bounds__(256) void prefix_kernel(float* __restrict__ KVc,
                                                     float* __restrict__ Kc) {
  const int h = blockIdx.x, t = threadIdx.x;
  for (int e = t; e < MF_ * DH_; e += 256) {
    float run = 0.f;
    for (int c = 0; c < NC_; ++c) {
      float* p = KVc + ((size_t)(h * NC_ + c)) * MF_ * DH_ + e;
      float tmp = *p; *p = run; run += tmp;
    }
  }
  if (t < MF_) {
    float run = 0.f;
    for (int c = 0; c < NC_; ++c) {
      float* p = Kc + (size_t)(h * NC_ + c) * MF_ + t;
      float tmp = *p; *p = run; run += tmp;
    }
  }
}

// ---------------------------------------------------------------- attention out (MFMA)
// numT[d][s] = KVcT·PQ^T + V^T·tril(Tm)^T ; Aout[s][d] = numT[d][s]/den[s]  (bf16)
// LDS rows padded to 72 halves (144B = 16 mod 128) -> conflict-free b128 frag reads.
__global__ __launch_bounds__(256) void attn_mfma(const float* __restrict__ PQ,
                                                 const float* __restrict__ PK,
                                                 const float* __restrict__ V,
                                                 const float* __restrict__ KVcT,
                                                 const float* __restrict__ Kc,
                                                 ushortT* __restrict__ Aout) {
  const int cc = blockIdx.x, h = blockIdx.y, t = threadIdx.x;
  const int w = t >> 6, l = t & 63;
  const int lr = l & 15, q = l >> 4;

  __shared__ ushortT pqs[64 * 72];  // pq[s][m]
  __shared__ ushortT pks[64 * 72];  // pk[tt][m]
  __shared__ ushortT vts[64 * 72];  // v^T[d][t]
  __shared__ ushortT kvs[64 * 72];  // KVcT[d][m]
  __shared__ ushortT tms[64 * 72];  // tril(Tm)[s][tt]
  __shared__ float dpart[256];
  __shared__ float den[64];

  // ---- load & bf16-convert (pq/pk/kv straight rows; V transposed)
  for (int i = t; i < 1024; i += 256) {
    const int s = i >> 4, m4 = i & 15;
    f4 vq = *(const f4*)(PQ + (size_t)(cc * CT_ + s) * DM_ + h * MF_ + m4 * 4);
    f4 vk = *(const f4*)(PK + (size_t)(cc * CT_ + s) * DM_ + h * MF_ + m4 * 4);
    f4 vv = *(const f4*)(V  + (size_t)(cc * CT_ + s) * DM_ + h * DH_ + m4 * 4);
    f4 vg = *(const f4*)(KVcT + ((size_t)(h * NC_ + cc) * DH_ + s) * MF_ + m4 * 4);
    u32* p;
    p = (u32*)&pqs[s * 72 + m4 * 4]; p[0] = pk2(vq.x, vq.y); p[1] = pk2(vq.z, vq.w);
    p = (u32*)&pks[s * 72 + m4 * 4]; p[0] = pk2(vk.x, vk.y); p[1] = pk2(vk.z, vk.w);
    p = (u32*)&kvs[s * 72 + m4 * 4]; p[0] = pk2(vg.x, vg.y); p[1] = pk2(vg.z, vg.w);
    vts[(m4 * 4 + 0) * 72 + s] = f2b(vv.x);
    vts[(m4 * 4 + 1) * 72 + s] = f2b(vv.y);
    vts[(m4 * 4 + 2) * 72 + s] = f2b(vv.z);
    vts[(m4 * 4 + 3) * 72 + s] = f2b(vv.w);
  }
  __syncthreads();

  // ---- Tm = PQ @ PK^T (wave w: s-rows [16w,16w+16)); zero above diagonal
  {
    const int s0 = w * 16;
    s8 a0 = *(const s8*)&pqs[(s0 + lr) * 72 + q * 8];
    s8 a1 = *(const s8*)&pqs[(s0 + lr) * 72 + 32 + q * 8];
#pragma unroll
    for (int tb = 0; tb < 4; ++tb) {
      f4 c = (f4){0.f, 0.f, 0.f, 0.f};
      if (tb <= w) {
        s8 b0 = *(const s8*)&pks[(tb * 16 + lr) * 72 + q * 8];
        s8 b1 = *(const s8*)&pks[(tb * 16 + lr) * 72 + 32 + q * 8];
        c = __builtin_amdgcn_mfma_f32_16x16x32_bf16(a0, b0, c, 0, 0, 0);
        c = __builtin_amdgcn_mfma_f32_16x16x32_bf16(a1, b1, c, 0, 0, 0);
      }
#pragma unroll
      for (int r = 0; r < 4; ++r) {
        float v = c[r];
        if (tb == w && lr > q * 4 + r) v = 0.f;  // causal mask inside diag tile
        tms[(s0 + q * 4 + r) * 72 + tb * 16 + lr] = f2b(v);
      }
    }
  }
  __syncthreads();

  // ---- den[s] = pq[s]·Kc_prefix (fp32, from global) + rowsum(tril Tm) + eps
  {
    const int s = t >> 2, part = t & 3;
    float dp = 0.f;
    const u32* trow = (const u32*)&tms[s * 72 + part * 16];
#pragma unroll
    for (int j = 0; j < 8; ++j) {
      u32 u = trow[j];
      dp += bu2f((ushortT)(u & 0xffffu)) + bu2f((ushortT)(u >> 16));
    }
    const f4* pq4 = (const f4*)(PQ + (size_t)(cc * CT_ + s) * DM_ + h * MF_ + part * 16);
    const f4* kc4 = (const f4*)(Kc + (size_t)(h * NC_ + cc) * MF_ + part * 16);
#pragma unroll
    for (int j = 0; j < 4; ++j) {
      f4 a = pq4[j], b = kc4[j];
      dp += a.x * b.x + a.y * b.y + a.z * b.z + a.w * b.w;
    }
    dpart[t] = dp;
  }
  __syncthreads();
  if (t < 64)
    den[t] = dpart[4 * t] + dpart[4 * t + 1] + dpart[4 * t + 2] + dpart[4 * t + 3] + EPS_;
  __syncthreads();

  // ---- numT[d][s] (wave w: d-rows [16w,16w+16)), divide, store bf16
  {
    const int d0 = w * 16;
    const int drow = d0 + lr;
    s8 akv0 = *(const s8*)&kvs[drow * 72 + q * 8];
    s8 akv1 = *(const s8*)&kvs[drow * 72 + 32 + q * 8];
    s8 av0  = *(const s8*)&vts[drow * 72 + q * 8];
    s8 av1  = *(const s8*)&vts[drow * 72 + 32 + q * 8];
#pragma unroll
    for (int sb = 0; sb < 4; ++sb) {
      const int srow = sb * 16 + lr;
      s8 bq0 = *(const s8*)&pqs[srow * 72 + q * 8];
      s8 bq1 = *(const s8*)&pqs[srow * 72 + 32 + q * 8];
      s8 bt0 = *(const s8*)&tms[srow * 72 + q * 8];
      s8 bt1 = *(const s8*)&tms[srow * 72 + 32 + q * 8];
      f4 c = (f4){0.f, 0.f, 0.f, 0.f};
      c = __builtin_amdgcn_mfma_f32_16x16x32_bf16(akv0, bq0, c, 0, 0, 0);
      c = __builtin_amdgcn_mfma_f32_16x16x32_bf16(akv1, bq1, c, 0, 0, 0);
      c = __builtin_amdgcn_mfma_f32_16x16x32_bf16(av0, bt0, c, 0, 0, 0);
      c = __builtin_amdgcn_mfma_f32_16x16x32_bf16(av1, bt1, c, 0, 0, 0);
      const float inv = 1.f / den[srow];
      u32x2 o;
      o.x = pk2(c[0] * inv, c[1] * inv);
      o.y = pk2(c[2] * inv, c[3] * inv);
      *(u32x2*)(Aout + (size_t)(cc * CT_ + srow) * DM_ + h * DH_ + d0 + q * 4) = o;
    }
  }
}

// ---------------------------------------------------------------- LayerNorm (dual out)
__global__ __launch_bounds__(256) void ln_kernel(const float* __restrict__ X,
                                                 const float* __restrict__ g,
                                                 const float* __restrict__ be,
                                                 float* __restrict__ outF,
                                                 ushortT* __restrict__ outB) {
  const int s = blockIdx.x, t = threadIdx.x;
  float v0 = X[(size_t)s * DM_ + t];
  float v1 = X[(size_t)s * DM_ + 256 + t];
  float sum = v0 + v1, sq = v0 * v0 + v1 * v1;
  for (int off = 32; off > 0; off >>= 1) {
    sum += __shfl_down(sum, off);
    sq += __shfl_down(sq, off);
  }
  __shared__ float ssum[4], ssq[4];
  __shared__ float smean, srstd;
  const int w = t >> 6;
  if ((t & 63) == 0) { ssum[w] = sum; ssq[w] = sq; }
  __syncthreads();
  if (t == 0) {
    float S1 = ssum[0] + ssum[1] + ssum[2] + ssum[3];
    float S2 = ssq[0] + ssq[1] + ssq[2] + ssq[3];
    float mu = S1 / DM_;
    float var = S2 / DM_ - mu * mu;
    smean = mu;
    srstd = rsqrtf(var + LN_EPS_);
  }
  __syncthreads();
  const float mu = smean, rs = srstd;
  float o0 = (v0 - mu) * rs * g[t] + be[t];
  float o1 = (v1 - mu) * rs * g[256 + t] + be[256 + t];
  outF[(size_t)s * DM_ + t] = o0;
  outF[(size_t)s * DM_ + 256 + t] = o1;
  if (outB) {
    outB[(size_t)s * DM_ + t] = f2b(o0);
    outB[(size_t)s * DM_ + 256 + t] = f2b(o1);
  }
}

// ---------------------------------------------------------------- launch
extern "C" void kernel_launch(void* const* d_in, const int* in_sizes, int n_in,
                              void* d_out, int out_size, void* d_ws, size_t ws_size,
                              hipStream_t stream) {
  const float* x    = (const float*)d_in[0];
  const float* Wq   = (const float*)d_in[1];
  const float* Wk   = (const float*)d_in[2];
  const float* Wv   = (const float*)d_in[3];
  const float* Wo   = (const float*)d_in[4];
  const float* W1   = (const float*)d_in[5];
  const float* W2   = (const float*)d_in[6];
  const float* bq   = (const float*)d_in[7];
  const float* bk   = (const float*)d_in[8];
  const float* bv   = (const float*)d_in[9];
  const float* bo   = (const float*)d_in[10];
  const float* b1   = (const float*)d_in[11];
  const float* b2   = (const float*)d_in[12];
  const float* g1   = (const float*)d_in[13];
  const float* be1  = (const float*)d_in[14];
  const float* g2   = (const float*)d_in[15];
  const float* be2  = (const float*)d_in[16];
  const float* omg  = (const float*)d_in[17];
  float* out = (float*)d_out;

  const size_t MB = 1048576;
  float* f    = (float*)d_ws;
  float* cur  = f;
  float* qb   = f + 1 * MB;
  float* kb   = f + 2 * MB;
  float* vb   = f + 3 * MB;
  float* pqb  = f + 4 * MB;
  float* pkb  = f + 5 * MB;
  float* ln1  = f + 6 * MB;
  float* KVcb = f + 7 * MB;                 // [H,NC,DH,MF] (transposed)
  float* Kcb  = f + 8 * MB;
  float* tmp1 = kb;
  ushortT* u  = (ushortT*)(f + 8 * MB + 16384);
  ushortT* curb = u;
  ushortT* qbb  = u + 1 * MB;
  ushortT* ln1b = u + 2 * MB;
  ushortT* wb   = u + 3 * MB;
  ushortT* ffb  = (ushortT*)pqb;

  const size_t LS = 3145728;
  const size_t W1OFF = 1048576, W2OFF = 2097152, WOOFF = 786432;

  copy_in<<<S_ * DM_ / 256, 256, 0, stream>>>(x, cur, curb);

  {
    P4 s4; s4.p[0] = Wq; s4.p[1] = Wk; s4.p[2] = Wv; s4.p[3] = Wo;
    tcast<<<dim3(16, 16, 8), 256, 0, stream>>>(s4, DM_ * DM_, 4, wb, LS, DM_ * DM_, DM_, DM_);
    P4 s1; s1.p[0] = W1; s1.p[1] = W1; s1.p[2] = W1; s1.p[3] = W1;
    tcast<<<dim3(64, 16, 2), 256, 0, stream>>>(s1, DM_ * DFF_, 1, wb + W1OFF, LS, 0, DM_, DFF_);
    P4 s2; s2.p[0] = W2; s2.p[1] = W2; s2.p[2] = W2; s2.p[3] = W2;
    tcast<<<dim3(16, 64, 2), 256, 0, stream>>>(s2, DFF_ * DM_, 1, wb + W2OFF, LS, 0, DFF_, DM_);
  }

  const dim3 gQKV(DM_ / 64, S_ / 64, 3);
  const dim3 g512(DM_ / 64, S_ / 64, 1);
  const dim3 gFF1(DFF_ / 64, S_ / 64, 1);
  const dim3 gAttn(NC_, H_);

  for (int l = 0; l < L_; ++l) {
    const ushortT* wl = wb + (size_t)l * LS;
    const size_t bo512 = (size_t)l * DM_;
    const size_t boFF = (size_t)l * DFF_;

    mgemm<false, false, false><<<gQKV, 256, 0, stream>>>(
        curb, wl, bq + bo512, bk + bo512, bv + bo512, nullptr, qb, nullptr, DM_, DM_);

    favor2<<<dim3(S_, 2), 512, 0, stream>>>(qb, kb, omg + (size_t)l * DH_ * MF_, pqb, pkb);
    chunk_sums<<<gAttn, 256, 0, stream>>>(pkb, vb, KVcb, Kcb);
    prefix_kernel<<<H_, 256, 0, stream>>>(KVcb, Kcb);
    attn_mfma<<<gAttn, 256, 0, stream>>>(pqb, pkb, vb, KVcb, Kcb, qbb);

    mgemm<false, true, false><<<g512, 256, 0, stream>>>(
        qbb, wl + WOOFF, bo + bo512, nullptr, nullptr, cur, tmp1, nullptr, DM_, DM_);
    ln_kernel<<<S_, 256, 0, stream>>>(tmp1, g1 + bo512, be1 + bo512, ln1, ln1b);

    mgemm<true, false, true><<<gFF1, 256, 0, stream>>>(
        ln1b, wl + W1OFF, b1 + boFF, nullptr, nullptr, nullptr, nullptr, ffb, DM_, DFF_);
    mgemm<false, true, false><<<g512, 256, 0, stream>>>(
        ffb, wl + W2OFF, b2 + bo512, nullptr, nullptr, ln1, tmp1, nullptr, DFF_, DM_);

    const bool last = (l == L_ - 1);
    ln_kernel<<<S_, 256, 0, stream>>>(tmp1, g2 + bo512, be2 + bo512,
                                      last ? out : cur, last ? nullptr : curb);
  }
}

// Round 5
// 249.430 us; speedup vs baseline: 3.7554x; 1.4481x over previous
//
#include <hip/hip_runtime.h>
#include <hip/hip_bf16.h>

#define S_  2048
#define DM_ 512
#define H_  8
#define DH_ 64
#define MF_ 64
#define DFF_ 2048
#define L_  2
#define CT_ 64
#define NC_ (S_ / CT_)
#define EPS_ 1e-6f
#define LN_EPS_ 1e-5f

typedef unsigned short ushortT;
typedef unsigned int u32;
typedef float f4 __attribute__((ext_vector_type(4)));
typedef short s8 __attribute__((ext_vector_type(8)));
typedef u32 u32x2 __attribute__((ext_vector_type(2)));

__device__ __forceinline__ ushortT f2b(float f) {
  union { float f; unsigned u; } v; v.f = f;
  unsigned r = v.u + 0x7fffu + ((v.u >> 16) & 1u);  // RNE
  return (ushortT)(r >> 16);
}
__device__ __forceinline__ float bu2f(ushortT h) {
  union { unsigned u; float f; } v; v.u = ((unsigned)h) << 16; return v.f;
}
__device__ __forceinline__ u32 pk2(float a, float b) {
  return (u32)f2b(a) | ((u32)f2b(b) << 16);
}

// ---------------------------------------------------------------- copy in
__global__ __launch_bounds__(256) void copy_in(const float* __restrict__ x,
                                               float* __restrict__ cur,
                                               ushortT* __restrict__ curb) {
  int i = blockIdx.x * 256 + threadIdx.x;
  float v = x[i];
  cur[i] = v;
  curb[i] = f2b(v);
}

// ---------------------------------------------------------------- weight transpose+cast
struct P4 { const float* p[4]; };
__global__ __launch_bounds__(256) void tcast(P4 srcs, int perLayer, int nper,
                                             ushortT* __restrict__ dstb,
                                             size_t layerStride, size_t wStride,
                                             int K, int N) {
  const int z = blockIdx.z;
  const int widx = (nper == 4) ? (z & 3) : 0;
  const int l = (nper == 4) ? (z >> 2) : z;
  const float* src = srcs.p[widx] + (size_t)l * perLayer;
  ushortT* dst = dstb + (size_t)l * layerStride + (size_t)widx * wStride;
  __shared__ ushortT tile[32][33];
  const int t = threadIdx.x;
  const int c = t & 31, r0 = t >> 5;
  const int n0 = blockIdx.x * 32, k0 = blockIdx.y * 32;
#pragma unroll
  for (int i = 0; i < 4; ++i) {
    int r = r0 + 8 * i;
    tile[r][c] = f2b(src[(size_t)(k0 + r) * N + n0 + c]);
  }
  __syncthreads();
#pragma unroll
  for (int i = 0; i < 4; ++i) {
    int r = r0 + 8 * i;
    dst[(size_t)(n0 + r) * K + k0 + c] = tile[c][r];
  }
}

// ---------------------------------------------------------------- MFMA GEMM (full-K)
template<bool RELU, bool HAS_RES, bool OUT_BF16>
__global__ __launch_bounds__(256) void mgemm(
    const ushortT* __restrict__ A, const ushortT* __restrict__ Wt,
    const float* __restrict__ bq_, const float* __restrict__ bk_,
    const float* __restrict__ bv_, const float* __restrict__ Res,
    float* __restrict__ Cf, ushortT* __restrict__ Cb, int K, int N) {
  __shared__ ushortT sA[2][2048];
  __shared__ ushortT sB[2][2048];
  const int t = threadIdx.x;
  const int w = t >> 6, l = t & 63;
  const int wm = w >> 1, wn = w & 1;
  const int n0 = blockIdx.x * 64, m0 = blockIdx.y * 64;
  const int z = blockIdx.z;
  const ushortT* Wz = Wt + (size_t)z * K * N;
  const float* bias = (z == 0) ? bq_ : (z == 1 ? bk_ : bv_);

  const int rs = w * 16 + (l >> 2);
  const int qs = (l & 3) ^ ((rs >> 1) & 3);
  const ushortT* gA = A  + (size_t)(m0 + rs) * K + qs * 8;
  const ushortT* gB = Wz + (size_t)(n0 + rs) * K + qs * 8;

  const int Ra = wm * 32 + (l & 15);
  const int Rb = wn * 32 + (l & 15);
  const int qq = l >> 4;
  const int aoff = (Ra * 4 + (qq ^ ((Ra >> 1) & 3))) * 8;
  const int boff = (Rb * 4 + (qq ^ ((Rb >> 1) & 3))) * 8;

  f4 acc[2][2];
#pragma unroll
  for (int i = 0; i < 2; ++i)
#pragma unroll
    for (int j = 0; j < 2; ++j) acc[i][j] = (f4){0.f, 0.f, 0.f, 0.f};

  auto stage = [&](int buf, int ko) {
    __builtin_amdgcn_global_load_lds(
        (const __attribute__((address_space(1))) void*)(gA + ko),
        (__attribute__((address_space(3))) void*)(&sA[buf][w * 512]), 16, 0, 0);
    __builtin_amdgcn_global_load_lds(
        (const __attribute__((address_space(1))) void*)(gB + ko),
        (__attribute__((address_space(3))) void*)(&sB[buf][w * 512]), 16, 0, 0);
  };

  stage(0, 0);
  const int nk = K >> 5;
  for (int ks = 0; ks < nk; ++ks) {
    __syncthreads();
    if (ks + 1 < nk) stage((ks + 1) & 1, (ks + 1) * 32);
    const ushortT* pa = sA[ks & 1];
    const ushortT* pb = sB[ks & 1];
    s8 a0 = *(const s8*)(pa + aoff);
    s8 a1 = *(const s8*)(pa + aoff + 512);
    s8 b0 = *(const s8*)(pb + boff);
    s8 b1 = *(const s8*)(pb + boff + 512);
    acc[0][0] = __builtin_amdgcn_mfma_f32_16x16x32_bf16(a0, b0, acc[0][0], 0, 0, 0);
    acc[0][1] = __builtin_amdgcn_mfma_f32_16x16x32_bf16(a0, b1, acc[0][1], 0, 0, 0);
    acc[1][0] = __builtin_amdgcn_mfma_f32_16x16x32_bf16(a1, b0, acc[1][0], 0, 0, 0);
    acc[1][1] = __builtin_amdgcn_mfma_f32_16x16x32_bf16(a1, b1, acc[1][1], 0, 0, 0);
  }

  const size_t outz = (size_t)z * S_ * N;
  const int colb = n0 + wn * 32 + (l & 15);
  const int rowb = m0 + wm * 32 + ((l >> 4) << 2);
#pragma unroll
  for (int mt = 0; mt < 2; ++mt) {
#pragma unroll
    for (int nt = 0; nt < 2; ++nt) {
      const int c = colb + nt * 16;
      const float bv = bias[c];
#pragma unroll
      for (int r = 0; r < 4; ++r) {
        const int rr = rowb + mt * 16 + r;
        float v = acc[mt][nt][r] + bv;
        if (HAS_RES) v += Res[(size_t)rr * N + c];
        if (RELU) v = fmaxf(v, 0.f);
        if (OUT_BF16) Cb[outz + (size_t)rr * N + c] = f2b(v);
        else          Cf[outz + (size_t)rr * N + c] = v;
      }
    }
  }
}

// ---------------------------------------------------------------- MFMA GEMM partial (split-K)
// PS[z][M][N] += A[:, zKS:(z+1)KS] @ Wt[:, zKS:(z+1)KS]^T  (plain store, no bias)
__global__ __launch_bounds__(256) void mgemm_part(
    const ushortT* __restrict__ A, const ushortT* __restrict__ Wt,
    float* __restrict__ PS, int K, int N, int KS) {
  __shared__ ushortT sA[2][2048];
  __shared__ ushortT sB[2][2048];
  const int t = threadIdx.x;
  const int w = t >> 6, l = t & 63;
  const int wm = w >> 1, wn = w & 1;
  const int n0 = blockIdx.x * 64, m0 = blockIdx.y * 64;
  const int z = blockIdx.z;

  const int rs = w * 16 + (l >> 2);
  const int qs = (l & 3) ^ ((rs >> 1) & 3);
  const ushortT* gA = A  + (size_t)(m0 + rs) * K + z * KS + qs * 8;
  const ushortT* gB = Wt + (size_t)(n0 + rs) * K + z * KS + qs * 8;

  const int Ra = wm * 32 + (l & 15);
  const int Rb = wn * 32 + (l & 15);
  const int qq = l >> 4;
  const int aoff = (Ra * 4 + (qq ^ ((Ra >> 1) & 3))) * 8;
  const int boff = (Rb * 4 + (qq ^ ((Rb >> 1) & 3))) * 8;

  f4 acc[2][2];
#pragma unroll
  for (int i = 0; i < 2; ++i)
#pragma unroll
    for (int j = 0; j < 2; ++j) acc[i][j] = (f4){0.f, 0.f, 0.f, 0.f};

  auto stage = [&](int buf, int ko) {
    __builtin_amdgcn_global_load_lds(
        (const __attribute__((address_space(1))) void*)(gA + ko),
        (__attribute__((address_space(3))) void*)(&sA[buf][w * 512]), 16, 0, 0);
    __builtin_amdgcn_global_load_lds(
        (const __attribute__((address_space(1))) void*)(gB + ko),
        (__attribute__((address_space(3))) void*)(&sB[buf][w * 512]), 16, 0, 0);
  };

  stage(0, 0);
  const int nk = KS >> 5;
  for (int ks = 0; ks < nk; ++ks) {
    __syncthreads();
    if (ks + 1 < nk) stage((ks + 1) & 1, (ks + 1) * 32);
    const ushortT* pa = sA[ks & 1];
    const ushortT* pb = sB[ks & 1];
    s8 a0 = *(const s8*)(pa + aoff);
    s8 a1 = *(const s8*)(pa + aoff + 512);
    s8 b0 = *(const s8*)(pb + boff);
    s8 b1 = *(const s8*)(pb + boff + 512);
    acc[0][0] = __builtin_amdgcn_mfma_f32_16x16x32_bf16(a0, b0, acc[0][0], 0, 0, 0);
    acc[0][1] = __builtin_amdgcn_mfma_f32_16x16x32_bf16(a0, b1, acc[0][1], 0, 0, 0);
    acc[1][0] = __builtin_amdgcn_mfma_f32_16x16x32_bf16(a1, b0, acc[1][0], 0, 0, 0);
    acc[1][1] = __builtin_amdgcn_mfma_f32_16x16x32_bf16(a1, b1, acc[1][1], 0, 0, 0);
  }

  float* out = PS + (size_t)z * S_ * N;
  const int colb = n0 + wn * 32 + (l & 15);
  const int rowb = m0 + wm * 32 + ((l >> 4) << 2);
#pragma unroll
  for (int mt = 0; mt < 2; ++mt) {
#pragma unroll
    for (int nt = 0; nt < 2; ++nt) {
      const int c = colb + nt * 16;
#pragma unroll
      for (int r = 0; r < 4; ++r)
        out[(size_t)(rowb + mt * 16 + r) * N + c] = acc[mt][nt][r];
    }
  }
}

// ---------------------------------------------------------------- reduce splits + bias + res + LN
__global__ __launch_bounds__(256) void redln(const float* __restrict__ PS, int nsplit,
                                             const float* __restrict__ bias,
                                             const float* __restrict__ res,
                                             const float* __restrict__ g,
                                             const float* __restrict__ be,
                                             float* __restrict__ outF,
                                             ushortT* __restrict__ outB) {
  const int s = blockIdx.x, t = threadIdx.x;
  float v0 = bias[t] + res[(size_t)s * DM_ + t];
  float v1 = bias[t + 256] + res[(size_t)s * DM_ + 256 + t];
  for (int z = 0; z < nsplit; ++z) {
    const float* p = PS + (size_t)z * S_ * DM_ + (size_t)s * DM_;
    v0 += p[t];
    v1 += p[256 + t];
  }
  float sum = v0 + v1, sq = v0 * v0 + v1 * v1;
  for (int off = 32; off > 0; off >>= 1) {
    sum += __shfl_down(sum, off);
    sq += __shfl_down(sq, off);
  }
  __shared__ float ssum[4], ssq[4];
  __shared__ float smean, srstd;
  const int w = t >> 6;
  if ((t & 63) == 0) { ssum[w] = sum; ssq[w] = sq; }
  __syncthreads();
  if (t == 0) {
    float S1 = ssum[0] + ssum[1] + ssum[2] + ssum[3];
    float S2 = ssq[0] + ssq[1] + ssq[2] + ssq[3];
    float mu = S1 / DM_;
    smean = mu;
    srstd = rsqrtf(S2 / DM_ - mu * mu + LN_EPS_);
  }
  __syncthreads();
  const float mu = smean, rs = srstd;
  float o0 = (v0 - mu) * rs * g[t] + be[t];
  float o1 = (v1 - mu) * rs * g[256 + t] + be[256 + t];
  outF[(size_t)s * DM_ + t] = o0;
  outF[(size_t)s * DM_ + 256 + t] = o1;
  if (outB) {
    outB[(size_t)s * DM_ + t] = f2b(o0);
    outB[(size_t)s * DM_ + 256 + t] = f2b(o1);
  }
}

// ---------------------------------------------------------------- FAVOR+ + chunk sums (fused, MFMA)
// Per (chunk c, head h): u=x@omegaT^T via MFMA, phi=exp(...), write pq/pk bf16;
// KVcT[d][m] = sum_t v[t,d] phi_k[t,m] via MFMA; Kc[m] = sum_t phi_k[t,m].
__global__ __launch_bounds__(256) void favor_cs(const ushortT* __restrict__ qkv,
                                                const ushortT* __restrict__ omgT,
                                                ushortT* __restrict__ PQb,
                                                ushortT* __restrict__ PKb,
                                                float* __restrict__ KVcT,
                                                float* __restrict__ Kc) {
  const int c = blockIdx.x, h = blockIdx.y, t = threadIdx.x;
  const int w = t >> 6, l = t & 63, lr = l & 15, q = l >> 4;
  __shared__ ushortT xq[64 * 72], xk[64 * 72], vT[64 * 72], omT[64 * 72];
  __shared__ ushortT pq[64 * 72], pk[64 * 72], pkT[64 * 72];
  __shared__ float nrm[128];

  const ushortT* qg = qkv + (size_t)(c * CT_) * DM_ + h * DH_;
  const ushortT* kg = qg + (size_t)S_ * DM_;
  const ushortT* vg = kg + (size_t)S_ * DM_;

  for (int i = t; i < 512; i += 256) {
    const int s = i >> 3, seg = i & 7;
    *(s8*)&xq[s * 72 + seg * 8] = *(const s8*)(qg + (size_t)s * DM_ + seg * 8);
    *(s8*)&xk[s * 72 + seg * 8] = *(const s8*)(kg + (size_t)s * DM_ + seg * 8);
    s8 av = *(const s8*)(vg + (size_t)s * DM_ + seg * 8);
#pragma unroll
    for (int j = 0; j < 8; ++j) vT[(seg * 8 + j) * 72 + s] = (ushortT)av[j];
    *(s8*)&omT[s * 72 + seg * 8] = *(const s8*)(omgT + s * 64 + seg * 8);
  }
  __syncthreads();

  // row norms (bf16 x): waves 0-1
  if (t < 128) {
    const ushortT* src = (t < 64) ? xq : xk;
    const int s = t & 63;
    float a = 0.f;
#pragma unroll
    for (int seg = 0; seg < 8; ++seg) {
      s8 vv = *(const s8*)(src + s * 72 + seg * 8);
#pragma unroll
      for (int j = 0; j < 8; ++j) {
        float f = bu2f((ushortT)vv[j]);
        a += f * f;
      }
    }
    nrm[t] = a;
  }
  __syncthreads();

  // u = x @ omegaT^T ; phi = exp(gam*u - 0.0625*nrm)*0.125
  {
    const float gam = 0.35355339059327373f;
    const int s0 = w * 16;
    s8 aq0 = *(const s8*)&xq[(s0 + lr) * 72 + q * 8];
    s8 aq1 = *(const s8*)&xq[(s0 + lr) * 72 + 32 + q * 8];
    s8 ak0 = *(const s8*)&xk[(s0 + lr) * 72 + q * 8];
    s8 ak1 = *(const s8*)&xk[(s0 + lr) * 72 + 32 + q * 8];
#pragma unroll
    for (int mt = 0; mt < 4; ++mt) {
      s8 b0 = *(const s8*)&omT[(mt * 16 + lr) * 72 + q * 8];
      s8 b1 = *(const s8*)&omT[(mt * 16 + lr) * 72 + 32 + q * 8];
      f4 cq = (f4){0.f, 0.f, 0.f, 0.f}, ck = (f4){0.f, 0.f, 0.f, 0.f};
      cq = __builtin_amdgcn_mfma_f32_16x16x32_bf16(aq0, b0, cq, 0, 0, 0);
      cq = __builtin_amdgcn_mfma_f32_16x16x32_bf16(aq1, b1, cq, 0, 0, 0);
      ck = __builtin_amdgcn_mfma_f32_16x16x32_bf16(ak0, b0, ck, 0, 0, 0);
      ck = __builtin_amdgcn_mfma_f32_16x16x32_bf16(ak1, b1, ck, 0, 0, 0);
#pragma unroll
      for (int r = 0; r < 4; ++r) {
        const int sr = s0 + q * 4 + r, mc = mt * 16 + lr;
        float vq = expf(gam * cq[r] - 0.0625f * nrm[sr]) * 0.125f;
        float vk = expf(gam * ck[r] - 0.0625f * nrm[64 + sr]) * 0.125f;
        pq[sr * 72 + mc] = f2b(vq);
        ushortT hk = f2b(vk);
        pk[sr * 72 + mc] = hk;
        pkT[mc * 72 + sr] = hk;
      }
    }
  }
  __syncthreads();

  // KVcT[d][m] = V^T @ PK  (A = vT rows d, B = pkT rows m)
  {
    const int d0 = w * 16;
    s8 a0 = *(const s8*)&vT[(d0 + lr) * 72 + q * 8];
    s8 a1 = *(const s8*)&vT[(d0 + lr) * 72 + 32 + q * 8];
    float* outb = KVcT + (size_t)(h * NC_ + c) * DH_ * MF_;
#pragma unroll
    for (int mt = 0; mt < 4; ++mt) {
      s8 b0 = *(const s8*)&pkT[(mt * 16 + lr) * 72 + q * 8];
      s8 b1 = *(const s8*)&pkT[(mt * 16 + lr) * 72 + 32 + q * 8];
      f4 cc = (f4){0.f, 0.f, 0.f, 0.f};
      cc = __builtin_amdgcn_mfma_f32_16x16x32_bf16(a0, b0, cc, 0, 0, 0);
      cc = __builtin_amdgcn_mfma_f32_16x16x32_bf16(a1, b1, cc, 0, 0, 0);
#pragma unroll
      for (int r = 0; r < 4; ++r)
        outb[(size_t)(d0 + q * 4 + r) * MF_ + mt * 16 + lr] = cc[r];
    }
  }
  if (t < 64) {
    float s = 0.f;
#pragma unroll
    for (int seg = 0; seg < 8; ++seg) {
      s8 vv = *(const s8*)&pkT[t * 72 + seg * 8];
#pragma unroll
      for (int j = 0; j < 8; ++j) s += bu2f((ushortT)vv[j]);
    }
    Kc[(size_t)(h * NC_ + c) * MF_ + t] = s;
  }
  for (int i = t; i < 512; i += 256) {
    const int s = i >> 3, seg = i & 7;
    *(s8*)(PQb + (size_t)(c * CT_ + s) * DM_ + h * MF_ + seg * 8) = *(const s8*)&pq[s * 72 + seg * 8];
    *(s8*)(PKb + (size_t)(c * CT_ + s) * DM_ + h * MF_ + seg * 8) = *(const s8*)&pk[s * 72 + seg * 8];
  }
}

// ---------------------------------------------------------------- prefix scan (register-resident)
__global__ __launch_bounds__(256) void prefix2(float* __restrict__ KVc,
                                               float* __restrict__ Kc) {
  const int h = blockIdx.x, seg = blockIdx.y, t = threadIdx.x;
  if (seg < 16) {
    float* base = KVc + (size_t)h * NC_ * MF_ * DH_ + seg * 256 + t;
    float v[NC_];
#pragma unroll
    for (int c = 0; c < NC_; ++c) v[c] = base[(size_t)c * MF_ * DH_];
    float run = 0.f;
#pragma unroll
    for (int c = 0; c < NC_; ++c) {
      float tmp = v[c];
      base[(size_t)c * MF_ * DH_] = run;
      run += tmp;
    }
  } else if (t < MF_) {
    float* base = Kc + (size_t)h * NC_ * MF_ + t;
    float v[NC_];
#pragma unroll
    for (int c = 0; c < NC_; ++c) v[c] = base[(size_t)c * MF_];
    float run = 0.f;
#pragma unroll
    for (int c = 0; c < NC_; ++c) {
      float tmp = v[c];
      base[(size_t)c * MF_] = run;
      run += tmp;
    }
  }
}

// ---------------------------------------------------------------- attention out (MFMA, bf16 in)
__global__ __launch_bounds__(256) void attn_mfma(const ushortT* __restrict__ PQ,
                                                 const ushortT* __restrict__ PK,
                                                 const ushortT* __restrict__ V,
                                                 const float* __restrict__ KVcT,
                                                 const float* __restrict__ Kc,
                                                 ushortT* __restrict__ Aout) {
  const int cc = blockIdx.x, h = blockIdx.y, t = threadIdx.x;
  const int w = t >> 6, l = t & 63;
  const int lr = l & 15, q = l >> 4;

  __shared__ ushortT pqs[64 * 72];
  __shared__ ushortT pks[64 * 72];
  __shared__ ushortT vts[64 * 72];
  __shared__ ushortT kvs[64 * 72];
  __shared__ ushortT tms[64 * 72];
  __shared__ float dpart[256];
  __shared__ float den[64];

  for (int i = t; i < 512; i += 256) {
    const int s = i >> 3, seg = i & 7;
    *(s8*)&pqs[s * 72 + seg * 8] = *(const s8*)(PQ + (size_t)(cc * CT_ + s) * DM_ + h * MF_ + seg * 8);
    *(s8*)&pks[s * 72 + seg * 8] = *(const s8*)(PK + (size_t)(cc * CT_ + s) * DM_ + h * MF_ + seg * 8);
    s8 av = *(const s8*)(V + (size_t)(cc * CT_ + s) * DM_ + h * DH_ + seg * 8);
#pragma unroll
    for (int j = 0; j < 8; ++j) vts[(seg * 8 + j) * 72 + s] = (ushortT)av[j];
    const float* kr = KVcT + (size_t)((h * NC_ + cc) * DH_ + s) * MF_ + seg * 8;
    f4 g0 = *(const f4*)kr;
    f4 g1 = *(const f4*)(kr + 4);
    u32* p = (u32*)&kvs[s * 72 + seg * 8];
    p[0] = pk2(g0.x, g0.y); p[1] = pk2(g0.z, g0.w);
    p[2] = pk2(g1.x, g1.y); p[3] = pk2(g1.z, g1.w);
  }
  __syncthreads();

  // Tm = PQ @ PK^T, tril
  {
    const int s0 = w * 16;
    s8 a0 = *(const s8*)&pqs[(s0 + lr) * 72 + q * 8];
    s8 a1 = *(const s8*)&pqs[(s0 + lr) * 72 + 32 + q * 8];
#pragma unroll
    for (int tb = 0; tb < 4; ++tb) {
      f4 c = (f4){0.f, 0.f, 0.f, 0.f};
      if (tb <= w) {
        s8 b0 = *(const s8*)&pks[(tb * 16 + lr) * 72 + q * 8];
        s8 b1 = *(const s8*)&pks[(tb * 16 + lr) * 72 + 32 + q * 8];
        c = __builtin_amdgcn_mfma_f32_16x16x32_bf16(a0, b0, c, 0, 0, 0);
        c = __builtin_amdgcn_mfma_f32_16x16x32_bf16(a1, b1, c, 0, 0, 0);
      }
#pragma unroll
      for (int r = 0; r < 4; ++r) {
        float v = c[r];
        if (tb == w && lr > q * 4 + r) v = 0.f;
        tms[(s0 + q * 4 + r) * 72 + tb * 16 + lr] = f2b(v);
      }
    }
  }
  __syncthreads();

  // den
  {
    const int s = t >> 2, part = t & 3;
    float dp = 0.f;
    const u32* trow = (const u32*)&tms[s * 72 + part * 16];
#pragma unroll
    for (int j = 0; j < 8; ++j) {
      u32 u = trow[j];
      dp += bu2f((ushortT)(u & 0xffffu)) + bu2f((ushortT)(u >> 16));
    }
    const u32* qrow = (const u32*)&pqs[s * 72 + part * 16];
    const f4* kc4 = (const f4*)(Kc + (size_t)(h * NC_ + cc) * MF_ + part * 16);
#pragma unroll
    for (int j = 0; j < 4; ++j) {
      f4 b = kc4[j];
      u32 ua = qrow[2 * j], ub = qrow[2 * j + 1];
      dp += bu2f((ushortT)(ua & 0xffffu)) * b.x + bu2f((ushortT)(ua >> 16)) * b.y +
            bu2f((ushortT)(ub & 0xffffu)) * b.z + bu2f((ushortT)(ub >> 16)) * b.w;
    }
    dpart[t] = dp;
  }
  __syncthreads();
  if (t < 64)
    den[t] = dpart[4 * t] + dpart[4 * t + 1] + dpart[4 * t + 2] + dpart[4 * t + 3] + EPS_;
  __syncthreads();

  // numT + divide + store
  {
    const int d0 = w * 16;
    const int drow = d0 + lr;
    s8 akv0 = *(const s8*)&kvs[drow * 72 + q * 8];
    s8 akv1 = *(const s8*)&kvs[drow * 72 + 32 + q * 8];
    s8 av0  = *(const s8*)&vts[drow * 72 + q * 8];
    s8 av1  = *(const s8*)&vts[drow * 72 + 32 + q * 8];
#pragma unroll
    for (int sb = 0; sb < 4; ++sb) {
      const int srow = sb * 16 + lr;
      s8 bq0 = *(const s8*)&pqs[srow * 72 + q * 8];
      s8 bq1 = *(const s8*)&pqs[srow * 72 + 32 + q * 8];
      s8 bt0 = *(const s8*)&tms[srow * 72 + q * 8];
      s8 bt1 = *(const s8*)&tms[srow * 72 + 32 + q * 8];
      f4 c = (f4){0.f, 0.f, 0.f, 0.f};
      c = __builtin_amdgcn_mfma_f32_16x16x32_bf16(akv0, bq0, c, 0, 0, 0);
      c = __builtin_amdgcn_mfma_f32_16x16x32_bf16(akv1, bq1, c, 0, 0, 0);
      c = __builtin_amdgcn_mfma_f32_16x16x32_bf16(av0, bt0, c, 0, 0, 0);
      c = __builtin_amdgcn_mfma_f32_16x16x32_bf16(av1, bt1, c, 0, 0, 0);
      const float inv = 1.f / den[srow];
      u32x2 o;
      o.x = pk2(c[0] * inv, c[1] * inv);
      o.y = pk2(c[2] * inv, c[3] * inv);
      *(u32x2*)(Aout + (size_t)(cc * CT_ + srow) * DM_ + h * DH_ + d0 + q * 4) = o;
    }
  }
}

// ---------------------------------------------------------------- launch
extern "C" void kernel_launch(void* const* d_in, const int* in_sizes, int n_in,
                              void* d_out, int out_size, void* d_ws, size_t ws_size,
                              hipStream_t stream) {
  const float* x    = (const float*)d_in[0];
  const float* Wq   = (const float*)d_in[1];
  const float* Wk   = (const float*)d_in[2];
  const float* Wv   = (const float*)d_in[3];
  const float* Wo   = (const float*)d_in[4];
  const float* W1   = (const float*)d_in[5];
  const float* W2   = (const float*)d_in[6];
  const float* bq   = (const float*)d_in[7];
  const float* bk   = (const float*)d_in[8];
  const float* bv   = (const float*)d_in[9];
  const float* bo   = (const float*)d_in[10];
  const float* b1   = (const float*)d_in[11];
  const float* b2   = (const float*)d_in[12];
  const float* g1   = (const float*)d_in[13];
  const float* be1  = (const float*)d_in[14];
  const float* g2   = (const float*)d_in[15];
  const float* be2  = (const float*)d_in[16];
  const float* omg  = (const float*)d_in[17];
  float* out = (float*)d_out;

  const size_t MB = 1048576;
  float* f    = (float*)d_ws;
  float* cur  = f;                 // [S,DM] fp32
  float* ln1  = f + 1 * MB;        // [S,DM] fp32
  float* KVcb = f + 2 * MB;        // [H,NC,DH,MF] fp32
  float* Kcb  = f + 3 * MB;        // [H,NC,MF]
  float* PS   = f + 3 * MB + 16384;  // up to 4 splits × [S,DM] fp32

  ushortT* u    = (ushortT*)(f + 8 * MB);
  ushortT* curb = u;               // [S,DM]
  ushortT* qkb  = u + 1 * MB;      // [3][S,DM] q,k,v
  ushortT* pqb  = u + 4 * MB;      // [S,DM]
  ushortT* pkb  = u + 5 * MB;
  ushortT* qbb  = u + 6 * MB;      // attn out
  ushortT* ln1b = u + 7 * MB;
  ushortT* ffb  = u + 8 * MB;      // [S,DFF] (4M)
  ushortT* wb   = u + 12 * MB;     // transposed weights (2×LS)
  ushortT* omgTb = wb + 2 * 3145728;  // [L][M][DH]

  const size_t LS = 3145728;
  const size_t W1OFF = 1048576, W2OFF = 2097152, WOOFF = 786432;

  copy_in<<<S_ * DM_ / 256, 256, 0, stream>>>(x, cur, curb);

  {
    P4 s4; s4.p[0] = Wq; s4.p[1] = Wk; s4.p[2] = Wv; s4.p[3] = Wo;
    tcast<<<dim3(16, 16, 8), 256, 0, stream>>>(s4, DM_ * DM_, 4, wb, LS, DM_ * DM_, DM_, DM_);
    P4 s1; s1.p[0] = W1; s1.p[1] = W1; s1.p[2] = W1; s1.p[3] = W1;
    tcast<<<dim3(64, 16, 2), 256, 0, stream>>>(s1, DM_ * DFF_, 1, wb + W1OFF, LS, 0, DM_, DFF_);
    P4 s2; s2.p[0] = W2; s2.p[1] = W2; s2.p[2] = W2; s2.p[3] = W2;
    tcast<<<dim3(16, 64, 2), 256, 0, stream>>>(s2, DFF_ * DM_, 1, wb + W2OFF, LS, 0, DFF_, DM_);
    P4 sm; sm.p[0] = omg; sm.p[1] = omg; sm.p[2] = omg; sm.p[3] = omg;
    tcast<<<dim3(2, 2, 2), 256, 0, stream>>>(sm, DH_ * MF_, 1, omgTb, DH_ * MF_, 0, DH_, MF_);
  }

  const dim3 gQKV(DM_ / 64, S_ / 64, 3);
  const dim3 gFF1(DFF_ / 64, S_ / 64, 1);
  const dim3 gWo(DM_ / 64, S_ / 64, 2);
  const dim3 gW2(DM_ / 64, S_ / 64, 4);
  const dim3 gAttn(NC_, H_);
  const dim3 gPre(H_, 17);

  for (int l = 0; l < L_; ++l) {
    const ushortT* wl = wb + (size_t)l * LS;
    const size_t bo512 = (size_t)l * DM_;
    const size_t boFF = (size_t)l * DFF_;

    mgemm<false, false, true><<<gQKV, 256, 0, stream>>>(
        curb, wl, bq + bo512, bk + bo512, bv + bo512, nullptr, nullptr, qkb, DM_, DM_);

    favor_cs<<<gAttn, 256, 0, stream>>>(qkb, omgTb + (size_t)l * DH_ * MF_,
                                        pqb, pkb, KVcb, Kcb);
    prefix2<<<gPre, 256, 0, stream>>>(KVcb, Kcb);
    attn_mfma<<<gAttn, 256, 0, stream>>>(pqb, pkb, qkb + 2 * (size_t)S_ * DM_,
                                         KVcb, Kcb, qbb);

    mgemm_part<<<gWo, 256, 0, stream>>>(qbb, wl + WOOFF, PS, DM_, DM_, 256);
    redln<<<S_, 256, 0, stream>>>(PS, 2, bo + bo512, cur, g1 + bo512, be1 + bo512, ln1, ln1b);

    mgemm<true, false, true><<<gFF1, 256, 0, stream>>>(
        ln1b, wl + W1OFF, b1 + boFF, nullptr, nullptr, nullptr, nullptr, ffb, DM_, DFF_);

    mgemm_part<<<gW2, 256, 0, stream>>>(ffb, wl + W2OFF, PS, DFF_, DM_, 512);
    const bool last = (l == L_ - 1);
    redln<<<S_, 256, 0, stream>>>(PS, 4, b2 + bo512, ln1, g2 + bo512, be2 + bo512,
                                  last ? out : cur, last ? nullptr : curb);
  }
}